// Round 1
// baseline (10783.715 us; speedup 1.0000x reference)
//
#include <hip/hip_runtime.h>
#include <hip/hip_bf16.h>
#include <math.h>

// Problem constants (from reference)
constexpr int NN  = 100000;   // nodes
constexpr int EE  = 3200000;  // edges
constexpr int HID = 128;
constexpr int NG  = 512;      // 4*HID
constexpr int NOUT = 64;
constexpr int HOPS = 10;

// ---------------------------------------------------------------------------
// prep: transpose W_ih/W_hh to [K=128][512] layout, bsum = b_ih + b_hh
// ---------------------------------------------------------------------------
__global__ __launch_bounds__(256) void prep_kernel(
    const float* __restrict__ Wih, const float* __restrict__ Whh,
    const float* __restrict__ bih, const float* __restrict__ bhh,
    float* __restrict__ WtI, float* __restrict__ WtH, float* __restrict__ bsum)
{
    int i = blockIdx.x * 256 + threadIdx.x;   // 65536 = 128*512
    int k = i >> 9;
    int c = i & 511;
    WtI[i] = Wih[c * 128 + k];
    WtH[i] = Whh[c * 128 + k];
    if (i < NG) bsum[i] = bih[i] + bhh[i];
}

// ---------------------------------------------------------------------------
// CSR build
// ---------------------------------------------------------------------------
__global__ __launch_bounds__(256) void hist_kernel(const int* __restrict__ erow,
                                                   int* __restrict__ deg)
{
    int e = blockIdx.x * 256 + threadIdx.x;
    atomicAdd(&deg[erow[e]], 1);
}

__global__ __launch_bounds__(1024) void scan_kernel(const int* __restrict__ deg,
                                                    int* __restrict__ rp,
                                                    int* __restrict__ cur)
{
    __shared__ int tmp[1024];
    __shared__ int carry_s;
    int t = threadIdx.x;
    if (t == 0) { carry_s = 0; rp[0] = 0; }
    __syncthreads();
    for (int base = 0; base < NN; base += 1024) {
        int i = base + t;
        int v = (i < NN) ? deg[i] : 0;
        tmp[t] = v;
        __syncthreads();
        for (int off = 1; off < 1024; off <<= 1) {
            int add = (t >= off) ? tmp[t - off] : 0;
            __syncthreads();
            tmp[t] += add;
            __syncthreads();
        }
        int incl = tmp[t] + carry_s;
        if (i < NN) { rp[i + 1] = incl; cur[i] = incl - v; }
        __syncthreads();
        if (t == 1023) carry_s = incl;
        __syncthreads();
    }
}

__global__ __launch_bounds__(256) void scatter_kernel(
    const int* __restrict__ erow, const int* __restrict__ ecol,
    const float* __restrict__ eval, int* __restrict__ cur,
    int* __restrict__ scol, float* __restrict__ sval)
{
    int e = blockIdx.x * 256 + threadIdx.x;
    int r = erow[e];
    int p = atomicAdd(&cur[r], 1);
    scol[p] = ecol[e];
    sval[p] = eval[e];
}

// ---------------------------------------------------------------------------
// Shared GEMM inner: acc[2 rows][4 gate-quads] += act(16x128 LDS) @ Wt[128][512]
// thread t: rows r0,r0+1 (r0=(t>>5)*2), cols cb..cb+3 of each 128-gate group
// ---------------------------------------------------------------------------
__device__ __forceinline__ void gemm_acc(const float* act, const float* __restrict__ Wt,
                                         int r0, int cb, float4 acc[2][4])
{
    for (int k = 0; k < 128; k += 4) {
        float4 a0 = *reinterpret_cast<const float4*>(act + r0 * 128 + k);
        float4 a1 = *reinterpret_cast<const float4*>(act + (r0 + 1) * 128 + k);
        const float a0s[4] = {a0.x, a0.y, a0.z, a0.w};
        const float a1s[4] = {a1.x, a1.y, a1.z, a1.w};
#pragma unroll
        for (int kk = 0; kk < 4; ++kk) {
#pragma unroll
            for (int q = 0; q < 4; ++q) {
                float4 w = *reinterpret_cast<const float4*>(Wt + (k + kk) * NG + q * 128 + cb);
                acc[0][q].x += a0s[kk] * w.x; acc[0][q].y += a0s[kk] * w.y;
                acc[0][q].z += a0s[kk] * w.z; acc[0][q].w += a0s[kk] * w.w;
                acc[1][q].x += a1s[kk] * w.x; acc[1][q].y += a1s[kk] * w.y;
                acc[1][q].z += a1s[kk] * w.z; acc[1][q].w += a1s[kk] * w.w;
            }
        }
    }
}

// gx = x @ W_ih^T + (b_ih + b_hh), computed once
__global__ __launch_bounds__(256) void gx_kernel(
    const float* __restrict__ x, const float* __restrict__ WtI,
    const float* __restrict__ bsum, float* __restrict__ gx)
{
    __shared__ __align__(16) float act[16 * 128];
    int t = threadIdx.x;
    int row0 = blockIdx.x * 16;
    int r0 = (t >> 5) * 2;
    int cb = (t & 31) * 4;

    float4 acc[2][4];
#pragma unroll
    for (int q = 0; q < 4; ++q) {
        float4 b = *reinterpret_cast<const float4*>(bsum + q * 128 + cb);
        acc[0][q] = b; acc[1][q] = b;
    }
    const float4* src = reinterpret_cast<const float4*>(x + (size_t)row0 * 128);
    float4* dst = reinterpret_cast<float4*>(act);
    dst[t] = src[t];
    dst[t + 256] = src[t + 256];
    __syncthreads();
    gemm_acc(act, WtI, r0, cb, acc);

#pragma unroll
    for (int rr = 0; rr < 2; ++rr) {
        int row = row0 + r0 + rr;
#pragma unroll
        for (int q = 0; q < 4; ++q)
            *reinterpret_cast<float4*>(gx + (size_t)row * NG + q * 128 + cb) = acc[rr][q];
    }
}

__device__ __forceinline__ float sigf(float v) { return 1.0f / (1.0f + __expf(-v)); }

// Fused (gates GEMM) + LSTM cell elementwise.
template<bool USE_GX, bool FIRST>
__global__ __launch_bounds__(256) void lstm_kernel(
    const float* __restrict__ x, const float* __restrict__ hin,
    float* __restrict__ cio, const float* __restrict__ gx,
    const float* __restrict__ WtI, const float* __restrict__ WtH,
    const float* __restrict__ bsum, float* __restrict__ hout)
{
    __shared__ __align__(16) float act[16 * 128];
    int t = threadIdx.x;
    int row0 = blockIdx.x * 16;
    int r0 = (t >> 5) * 2;
    int cb = (t & 31) * 4;

    float4 acc[2][4];
    if (USE_GX) {
#pragma unroll
        for (int rr = 0; rr < 2; ++rr) {
            int row = row0 + r0 + rr;
#pragma unroll
            for (int q = 0; q < 4; ++q)
                acc[rr][q] = *reinterpret_cast<const float4*>(gx + (size_t)row * NG + q * 128 + cb);
        }
    } else {
#pragma unroll
        for (int q = 0; q < 4; ++q) {
            float4 b = *reinterpret_cast<const float4*>(bsum + q * 128 + cb);
            acc[0][q] = b; acc[1][q] = b;
        }
    }

    if (!USE_GX) {
        const float4* src = reinterpret_cast<const float4*>(x + (size_t)row0 * 128);
        float4* dst = reinterpret_cast<float4*>(act);
        dst[t] = src[t];
        dst[t + 256] = src[t + 256];
        __syncthreads();
        gemm_acc(act, WtI, r0, cb, acc);
        __syncthreads();
    }
    if (!FIRST) {
        const float4* src = reinterpret_cast<const float4*>(hin + (size_t)row0 * 128);
        float4* dst = reinterpret_cast<float4*>(act);
        dst[t] = src[t];
        dst[t + 256] = src[t + 256];
        __syncthreads();
        gemm_acc(act, WtH, r0, cb, acc);
    }

#pragma unroll
    for (int rr = 0; rr < 2; ++rr) {
        int row = row0 + r0 + rr;
        float4 iv = acc[rr][0], fv = acc[rr][1], gv = acc[rr][2], ov = acc[rr][3];
        float4 cold;
        if (FIRST) { cold.x = 0.f; cold.y = 0.f; cold.z = 0.f; cold.w = 0.f; }
        else cold = *reinterpret_cast<const float4*>(cio + (size_t)row * HID + cb);
        float4 cn, hn;
        cn.x = sigf(fv.x) * cold.x + sigf(iv.x) * tanhf(gv.x);
        cn.y = sigf(fv.y) * cold.y + sigf(iv.y) * tanhf(gv.y);
        cn.z = sigf(fv.z) * cold.z + sigf(iv.z) * tanhf(gv.z);
        cn.w = sigf(fv.w) * cold.w + sigf(iv.w) * tanhf(gv.w);
        hn.x = sigf(ov.x) * tanhf(cn.x);
        hn.y = sigf(ov.y) * tanhf(cn.y);
        hn.z = sigf(ov.z) * tanhf(cn.z);
        hn.w = sigf(ov.w) * tanhf(cn.w);
        *reinterpret_cast<float4*>(cio + (size_t)row * HID + cb) = cn;
        *reinterpret_cast<float4*>(hout + (size_t)row * HID + cb) = hn;
    }
}

// ---------------------------------------------------------------------------
// SpMM: h_out[r,:] = sum_{e in row r} val[e] * h_in[col[e],:]
// one block (128 threads) per row; CSR -> no atomics
// ---------------------------------------------------------------------------
__global__ __launch_bounds__(128) void spmm_kernel(
    const int* __restrict__ rp, const int* __restrict__ scol,
    const float* __restrict__ sval, const float* __restrict__ hin,
    float* __restrict__ hout)
{
    int r = blockIdx.x;
    int t = threadIdx.x;
    int beg = rp[r], end = rp[r + 1];
    float acc = 0.f;
    for (int e = beg; e < end; ++e) {
        int c = scol[e];
        float v = sval[e];
        acc += v * hin[(size_t)c * HID + t];
    }
    hout[(size_t)r * HID + t] = acc;
}

// ---------------------------------------------------------------------------
// final: out = relu(h) @ fc_w^T + fc_b   [100000,128] x [64,128]^T -> [100000,64]
// 32 rows/block; fc_w transposed into LDS
// ---------------------------------------------------------------------------
__global__ __launch_bounds__(256) void final_kernel(
    const float* __restrict__ h, const float* __restrict__ fcw,
    const float* __restrict__ fcb, float* __restrict__ out)
{
    __shared__ __align__(16) float hl[32 * 128];
    __shared__ __align__(16) float wt[128 * 64];
    int t = threadIdx.x;
    int row0 = blockIdx.x * 32;

    // transpose fc_w [64][128] -> wt[k][o]
    {
        const float4* src = reinterpret_cast<const float4*>(fcw);
#pragma unroll
        for (int j = 0; j < 8; ++j) {
            int f4 = t + j * 256;           // 2048 float4 total
            float4 v = src[f4];
            int o = f4 >> 5;
            int k4 = (f4 & 31) * 4;
            wt[(k4 + 0) * 64 + o] = v.x;
            wt[(k4 + 1) * 64 + o] = v.y;
            wt[(k4 + 2) * 64 + o] = v.z;
            wt[(k4 + 3) * 64 + o] = v.w;
        }
    }
    // load h rows with relu
    {
        const float4* src = reinterpret_cast<const float4*>(h + (size_t)row0 * HID);
        float4* dst = reinterpret_cast<float4*>(hl);
#pragma unroll
        for (int j = 0; j < 4; ++j) {
            float4 v = src[t + j * 256];
            v.x = fmaxf(v.x, 0.f); v.y = fmaxf(v.y, 0.f);
            v.z = fmaxf(v.z, 0.f); v.w = fmaxf(v.w, 0.f);
            dst[t + j * 256] = v;
        }
    }
    __syncthreads();

    int ob = (t & 15) * 4;        // 0..60
    int r0 = (t >> 4) * 2;        // 0..30
    float4 acc0 = {0, 0, 0, 0}, acc1 = {0, 0, 0, 0};
    for (int k = 0; k < 128; ++k) {
        float4 w = *reinterpret_cast<const float4*>(wt + k * 64 + ob);
        float a0 = hl[r0 * 128 + k];
        float a1 = hl[(r0 + 1) * 128 + k];
        acc0.x += a0 * w.x; acc0.y += a0 * w.y; acc0.z += a0 * w.z; acc0.w += a0 * w.w;
        acc1.x += a1 * w.x; acc1.y += a1 * w.y; acc1.z += a1 * w.z; acc1.w += a1 * w.w;
    }
    float4 b = *reinterpret_cast<const float4*>(fcb + ob);
    acc0.x += b.x; acc0.y += b.y; acc0.z += b.z; acc0.w += b.w;
    acc1.x += b.x; acc1.y += b.y; acc1.z += b.z; acc1.w += b.w;
    *reinterpret_cast<float4*>(out + (size_t)(row0 + r0) * NOUT + ob) = acc0;
    *reinterpret_cast<float4*>(out + (size_t)(row0 + r0 + 1) * NOUT + ob) = acc1;
}

// ---------------------------------------------------------------------------
extern "C" void kernel_launch(void* const* d_in, const int* in_sizes, int n_in,
                              void* d_out, int out_size, void* d_ws, size_t ws_size,
                              hipStream_t stream)
{
    const float* x    = (const float*)d_in[0];
    const int*   erow = (const int*)d_in[1];
    const int*   ecol = (const int*)d_in[2];
    const float* eval = (const float*)d_in[3];
    const float* Wih  = (const float*)d_in[4];
    const float* Whh  = (const float*)d_in[5];
    const float* bih  = (const float*)d_in[6];
    const float* bhh  = (const float*)d_in[7];
    const float* fcw  = (const float*)d_in[8];
    const float* fcb  = (const float*)d_in[9];
    float* out = (float*)d_out;

    char* ws = (char*)d_ws;
    size_t off = 0;
    auto alloc = [&](size_t bytes) -> void* {
        void* p = ws + off;
        off = (off + bytes + 255) & ~(size_t)255;
        return p;
    };
    float* h_a  = (float*)alloc((size_t)NN * HID * 4);
    float* h_b  = (float*)alloc((size_t)NN * HID * 4);
    float* cbuf = (float*)alloc((size_t)NN * HID * 4);
    float* WtI  = (float*)alloc((size_t)NG * 128 * 4);
    float* WtH  = (float*)alloc((size_t)NG * 128 * 4);
    float* bsum = (float*)alloc((size_t)NG * 4);
    int*   rp   = (int*)alloc((size_t)(NN + 1) * 4);
    int*   deg  = (int*)alloc((size_t)NN * 4);
    int*   cur  = (int*)alloc((size_t)NN * 4);
    int*   scol = (int*)alloc((size_t)EE * 4);
    float* sval = (float*)alloc((size_t)EE * 4);
    float* gx   = (float*)alloc((size_t)NN * NG * 4);
    bool use_gx = (ws_size >= off);

    // prep (W transpose + bias sum)
    prep_kernel<<<256, 256, 0, stream>>>(Wih, Whh, bih, bhh, WtI, WtH, bsum);

    // CSR build
    hipMemsetAsync(deg, 0, (size_t)NN * 4, stream);
    hist_kernel<<<EE / 256, 256, 0, stream>>>(erow, deg);
    scan_kernel<<<1, 1024, 0, stream>>>(deg, rp, cur);
    scatter_kernel<<<EE / 256, 256, 0, stream>>>(erow, ecol, eval, cur, scol, sval);

    const int GEMM_GRID = NN / 16;   // 6250

    if (use_gx) {
        gx_kernel<<<GEMM_GRID, 256, 0, stream>>>(x, WtI, bsum, gx);
        // hop 0
        lstm_kernel<true, true><<<GEMM_GRID, 256, 0, stream>>>(x, h_b, cbuf, gx, WtI, WtH, bsum, h_a);
        spmm_kernel<<<NN, 128, 0, stream>>>(rp, scol, sval, h_a, h_b);
        for (int hop = 1; hop < HOPS; ++hop) {
            lstm_kernel<true, false><<<GEMM_GRID, 256, 0, stream>>>(x, h_b, cbuf, gx, WtI, WtH, bsum, h_a);
            spmm_kernel<<<NN, 128, 0, stream>>>(rp, scol, sval, h_a, h_b);
        }
    } else {
        lstm_kernel<false, true><<<GEMM_GRID, 256, 0, stream>>>(x, h_b, cbuf, nullptr, WtI, WtH, bsum, h_a);
        spmm_kernel<<<NN, 128, 0, stream>>>(rp, scol, sval, h_a, h_b);
        for (int hop = 1; hop < HOPS; ++hop) {
            lstm_kernel<false, false><<<GEMM_GRID, 256, 0, stream>>>(x, h_b, cbuf, nullptr, WtI, WtH, bsum, h_a);
            spmm_kernel<<<NN, 128, 0, stream>>>(rp, scol, sval, h_a, h_b);
        }
    }

    final_kernel<<<NN / 32, 256, 0, stream>>>(h_b, fcw, fcb, out);
}

// Round 2
// 3979.941 us; speedup vs baseline: 2.7095x; 2.7095x over previous
//
#include <hip/hip_runtime.h>
#include <hip/hip_bf16.h>
#include <math.h>

constexpr int NN  = 100000;   // nodes
constexpr int EE  = 3200000;  // edges
constexpr int HID = 128;
constexpr int NG  = 512;      // 4*HID
constexpr int NOUT = 64;
constexpr int HOPS = 10;

typedef __attribute__((ext_vector_type(8))) short short8;
typedef __attribute__((ext_vector_type(4))) float f32x4;

__device__ __forceinline__ ushort f2bf(float f) {
    uint u = __builtin_bit_cast(uint, f);
    u += 0x7fff + ((u >> 16) & 1);          // RNE
    return (ushort)(u >> 16);
}
__device__ __forceinline__ float bflo(uint u) { return __builtin_bit_cast(float, u << 16); }
__device__ __forceinline__ float bfhi(uint u) { return __builtin_bit_cast(float, u & 0xffff0000u); }

__device__ __forceinline__ float sigf(float v) { return 1.0f / (1.0f + __expf(-v)); }
__device__ __forceinline__ float tanh_fast(float x) {
    float t = __expf(-2.0f * fabsf(x));
    float r = (1.0f - t) / (1.0f + t);
    return copysignf(r, x);
}

__device__ __forceinline__ short8 load_frag(const ushort* p) {
    return *reinterpret_cast<const short8*>(p);
}
__device__ __forceinline__ f32x4 mfma16(short8 a, short8 b, f32x4 c) {
    return __builtin_amdgcn_mfma_f32_16x16x32_bf16(a, b, c, 0, 0, 0);
}

// ---------------------------------------------------------------------------
// fp32 -> bf16 conversion (vectorized), n4 = n/4
// ---------------------------------------------------------------------------
__global__ __launch_bounds__(256) void convert_bf16_kernel(
    const float* __restrict__ src, ushort* __restrict__ dst, int n4)
{
    int i = blockIdx.x * 256 + threadIdx.x;
    if (i < n4) {
        float4 v = reinterpret_cast<const float4*>(src)[i];
        ushort4 o;
        o.x = f2bf(v.x); o.y = f2bf(v.y); o.z = f2bf(v.z); o.w = f2bf(v.w);
        reinterpret_cast<ushort4*>(dst)[i] = o;
    }
}

__global__ __launch_bounds__(256) void bsum_kernel(
    const float* __restrict__ bih, const float* __restrict__ bhh, float* __restrict__ bsum)
{
    int i = blockIdx.x * 256 + threadIdx.x;
    if (i < NG) bsum[i] = bih[i] + bhh[i];
}

// ---------------------------------------------------------------------------
// CSR build
// ---------------------------------------------------------------------------
__global__ __launch_bounds__(256) void hist_kernel(const int* __restrict__ erow,
                                                   int* __restrict__ deg)
{
    int e = blockIdx.x * 256 + threadIdx.x;
    atomicAdd(&deg[erow[e]], 1);
}

__global__ __launch_bounds__(1024) void scan_kernel(const int* __restrict__ deg,
                                                    int* __restrict__ rp,
                                                    int* __restrict__ cur)
{
    __shared__ int tmp[1024];
    __shared__ int carry_s;
    int t = threadIdx.x;
    if (t == 0) { carry_s = 0; rp[0] = 0; }
    __syncthreads();
    for (int base = 0; base < NN; base += 1024) {
        int i = base + t;
        int v = (i < NN) ? deg[i] : 0;
        tmp[t] = v;
        __syncthreads();
        for (int off = 1; off < 1024; off <<= 1) {
            int add = (t >= off) ? tmp[t - off] : 0;
            __syncthreads();
            tmp[t] += add;
            __syncthreads();
        }
        int incl = tmp[t] + carry_s;
        if (i < NN) { rp[i + 1] = incl; cur[i] = incl - v; }
        __syncthreads();
        if (t == 1023) carry_s = incl;
        __syncthreads();
    }
}

__global__ __launch_bounds__(256) void scatter_kernel(
    const int* __restrict__ erow, const int* __restrict__ ecol,
    const float* __restrict__ eval, int* __restrict__ cur,
    int* __restrict__ scol, float* __restrict__ sval)
{
    int e = blockIdx.x * 256 + threadIdx.x;
    int r = erow[e];
    int p = atomicAdd(&cur[r], 1);
    scol[p] = ecol[e];
    sval[p] = eval[e];
}

// ---------------------------------------------------------------------------
// cell0: gates = x @ W_ih^T + bsum (MFMA), optional gx store, LSTM with c=0
// block = 256 threads = 4 waves, each wave: 16 rows x all 512 cols
// ---------------------------------------------------------------------------
template<bool WRITE_GX>
__global__ __launch_bounds__(256) void cell0_kernel(
    const ushort* __restrict__ xb, const ushort* __restrict__ Wib,
    const float* __restrict__ bsum, float* __restrict__ gx,
    float* __restrict__ cbuf, ushort* __restrict__ hout)
{
    const int t = threadIdx.x;
    const int l = t & 63;
    const int w = t >> 6;
    const int lr = l & 15;
    const int lk = l >> 4;
    const int row0 = blockIdx.x * 64 + w * 16;

    f32x4 acc[32];
#pragma unroll
    for (int n = 0; n < 32; ++n) {
        float b = bsum[n * 16 + lr];
        acc[n][0] = b; acc[n][1] = b; acc[n][2] = b; acc[n][3] = b;
    }

    const short8 z8 = {0,0,0,0,0,0,0,0};
    const int arow = row0 + lr;
    const bool aok = arow < NN;
    short8 ax[4];
#pragma unroll
    for (int ks = 0; ks < 4; ++ks)
        ax[ks] = aok ? load_frag(xb + (size_t)arow * HID + ks * 32 + lk * 8) : z8;

#pragma unroll
    for (int n = 0; n < 32; ++n) {
        const ushort* wp = Wib + (n * 16 + lr) * HID + lk * 8;
#pragma unroll
        for (int ks = 0; ks < 4; ++ks)
            acc[n] = mfma16(ax[ks], load_frag(wp + ks * 32), acc[n]);
    }

    if (WRITE_GX) {
#pragma unroll
        for (int n = 0; n < 32; ++n) {
#pragma unroll
            for (int j = 0; j < 4; ++j) {
                int row = row0 + lk * 4 + j;
                if (row < NN) gx[(size_t)row * NG + n * 16 + lr] = acc[n][j];
            }
        }
    }

#pragma unroll
    for (int n = 0; n < 8; ++n) {
#pragma unroll
        for (int j = 0; j < 4; ++j) {
            int row = row0 + lk * 4 + j;
            if (row < NN) {
                int col = n * 16 + lr;
                float iv = acc[n][j], gv = acc[n + 16][j], ov = acc[n + 24][j];
                float cn = sigf(iv) * tanh_fast(gv);
                float hn = sigf(ov) * tanh_fast(cn);
                cbuf[(size_t)row * HID + col] = cn;
                hout[(size_t)row * HID + col] = f2bf(hn);
            }
        }
    }
}

// ---------------------------------------------------------------------------
// lstm (hops 1..9): gates = gx + h @ W_hh^T (MFMA), fused LSTM elementwise
// ---------------------------------------------------------------------------
template<bool USE_GX>
__global__ __launch_bounds__(256) void lstm_mfma_kernel(
    const ushort* __restrict__ hb, const ushort* __restrict__ xb,
    const float* __restrict__ gx, const ushort* __restrict__ Whb,
    const ushort* __restrict__ Wib, const float* __restrict__ bsum,
    float* __restrict__ cbuf, ushort* __restrict__ hout)
{
    const int t = threadIdx.x;
    const int l = t & 63;
    const int w = t >> 6;
    const int lr = l & 15;
    const int lk = l >> 4;
    const int row0 = blockIdx.x * 64 + w * 16;

    f32x4 acc[32];
    if (USE_GX) {
#pragma unroll
        for (int n = 0; n < 32; ++n) {
#pragma unroll
            for (int j = 0; j < 4; ++j) {
                int row = row0 + lk * 4 + j;
                acc[n][j] = (row < NN) ? gx[(size_t)row * NG + n * 16 + lr] : 0.f;
            }
        }
    } else {
#pragma unroll
        for (int n = 0; n < 32; ++n) {
            float b = bsum[n * 16 + lr];
            acc[n][0] = b; acc[n][1] = b; acc[n][2] = b; acc[n][3] = b;
        }
    }

    const short8 z8 = {0,0,0,0,0,0,0,0};
    const int arow = row0 + lr;
    const bool aok = arow < NN;
    short8 ah[4];
#pragma unroll
    for (int ks = 0; ks < 4; ++ks)
        ah[ks] = aok ? load_frag(hb + (size_t)arow * HID + ks * 32 + lk * 8) : z8;
    short8 ax[4];
    if (!USE_GX) {
#pragma unroll
        for (int ks = 0; ks < 4; ++ks)
            ax[ks] = aok ? load_frag(xb + (size_t)arow * HID + ks * 32 + lk * 8) : z8;
    }

#pragma unroll
    for (int n = 0; n < 32; ++n) {
        const ushort* wp = Whb + (n * 16 + lr) * HID + lk * 8;
#pragma unroll
        for (int ks = 0; ks < 4; ++ks)
            acc[n] = mfma16(ah[ks], load_frag(wp + ks * 32), acc[n]);
        if (!USE_GX) {
            const ushort* wq = Wib + (n * 16 + lr) * HID + lk * 8;
#pragma unroll
            for (int ks = 0; ks < 4; ++ks)
                acc[n] = mfma16(ax[ks], load_frag(wq + ks * 32), acc[n]);
        }
    }

#pragma unroll
    for (int n = 0; n < 8; ++n) {
#pragma unroll
        for (int j = 0; j < 4; ++j) {
            int row = row0 + lk * 4 + j;
            if (row < NN) {
                int col = n * 16 + lr;
                float iv = acc[n][j], fv = acc[n + 8][j];
                float gv = acc[n + 16][j], ov = acc[n + 24][j];
                float cold = cbuf[(size_t)row * HID + col];
                float cn = sigf(fv) * cold + sigf(iv) * tanh_fast(gv);
                float hn = sigf(ov) * tanh_fast(cn);
                cbuf[(size_t)row * HID + col] = cn;
                hout[(size_t)row * HID + col] = f2bf(hn);
            }
        }
    }
}

// ---------------------------------------------------------------------------
// SpMM: hout[r,:] = sum_e val[e] * hin[col[e],:]   (bf16 in/out, fp32 accum)
// one wave per row, lane owns 2 features (dword)
// ---------------------------------------------------------------------------
__global__ __launch_bounds__(256) void spmm_kernel(
    const int* __restrict__ rp, const int* __restrict__ scol,
    const float* __restrict__ sval, const ushort* __restrict__ hin,
    ushort* __restrict__ hout)
{
    int r = blockIdx.x * 4 + (threadIdx.x >> 6);
    if (r >= NN) return;
    int l = threadIdx.x & 63;
    int beg = rp[r], end = rp[r + 1];

    float s0a = 0.f, s1a = 0.f, s0b = 0.f, s1b = 0.f;
    float s0c = 0.f, s1c = 0.f, s0d = 0.f, s1d = 0.f;
    int e = beg;
    for (; e + 4 <= end; e += 4) {
        int c0 = scol[e], c1 = scol[e + 1], c2 = scol[e + 2], c3 = scol[e + 3];
        float v0 = sval[e], v1 = sval[e + 1], v2 = sval[e + 2], v3 = sval[e + 3];
        uint g0 = *reinterpret_cast<const uint*>(hin + (size_t)c0 * HID + l * 2);
        uint g1 = *reinterpret_cast<const uint*>(hin + (size_t)c1 * HID + l * 2);
        uint g2 = *reinterpret_cast<const uint*>(hin + (size_t)c2 * HID + l * 2);
        uint g3 = *reinterpret_cast<const uint*>(hin + (size_t)c3 * HID + l * 2);
        s0a += v0 * bflo(g0); s1a += v0 * bfhi(g0);
        s0b += v1 * bflo(g1); s1b += v1 * bfhi(g1);
        s0c += v2 * bflo(g2); s1c += v2 * bfhi(g2);
        s0d += v3 * bflo(g3); s1d += v3 * bfhi(g3);
    }
    for (; e < end; ++e) {
        int c0 = scol[e];
        float v0 = sval[e];
        uint g0 = *reinterpret_cast<const uint*>(hin + (size_t)c0 * HID + l * 2);
        s0a += v0 * bflo(g0); s1a += v0 * bfhi(g0);
    }
    float s0 = (s0a + s0b) + (s0c + s0d);
    float s1 = (s1a + s1b) + (s1c + s1d);
    uint o = ((uint)f2bf(s1) << 16) | (uint)f2bf(s0);
    *reinterpret_cast<uint*>(hout + (size_t)r * HID + l * 2) = o;
}

// ---------------------------------------------------------------------------
// final: out = relu(h) @ fc_w^T + fc_b  (MFMA)
// ---------------------------------------------------------------------------
__global__ __launch_bounds__(256) void final_mfma_kernel(
    const ushort* __restrict__ hb, const ushort* __restrict__ fcwb,
    const float* __restrict__ fcb, float* __restrict__ out)
{
    const int t = threadIdx.x;
    const int l = t & 63;
    const int w = t >> 6;
    const int lr = l & 15;
    const int lk = l >> 4;
    const int row0 = blockIdx.x * 64 + w * 16;

    f32x4 acc[4];
#pragma unroll
    for (int n = 0; n < 4; ++n) {
        float b = fcb[n * 16 + lr];
        acc[n][0] = b; acc[n][1] = b; acc[n][2] = b; acc[n][3] = b;
    }

    const short8 z8 = {0,0,0,0,0,0,0,0};
    const int arow = row0 + lr;
    const bool aok = arow < NN;
    short8 a[4];
#pragma unroll
    for (int ks = 0; ks < 4; ++ks) {
        short8 v = aok ? load_frag(hb + (size_t)arow * HID + ks * 32 + lk * 8) : z8;
#pragma unroll
        for (int i = 0; i < 8; ++i) {
            ushort u = (ushort)v[i];
            if (u & 0x8000) v[i] = 0;   // relu in bf16
        }
        a[ks] = v;
    }

#pragma unroll
    for (int n = 0; n < 4; ++n) {
        const ushort* wp = fcwb + (n * 16 + lr) * HID + lk * 8;
#pragma unroll
        for (int ks = 0; ks < 4; ++ks)
            acc[n] = mfma16(a[ks], load_frag(wp + ks * 32), acc[n]);
    }

#pragma unroll
    for (int n = 0; n < 4; ++n) {
#pragma unroll
        for (int j = 0; j < 4; ++j) {
            int row = row0 + lk * 4 + j;
            if (row < NN) out[(size_t)row * NOUT + n * 16 + lr] = acc[n][j];
        }
    }
}

// ---------------------------------------------------------------------------
extern "C" void kernel_launch(void* const* d_in, const int* in_sizes, int n_in,
                              void* d_out, int out_size, void* d_ws, size_t ws_size,
                              hipStream_t stream)
{
    const float* x    = (const float*)d_in[0];
    const int*   erow = (const int*)d_in[1];
    const int*   ecol = (const int*)d_in[2];
    const float* eval = (const float*)d_in[3];
    const float* Wih  = (const float*)d_in[4];
    const float* Whh  = (const float*)d_in[5];
    const float* bih  = (const float*)d_in[6];
    const float* bhh  = (const float*)d_in[7];
    const float* fcw  = (const float*)d_in[8];
    const float* fcb  = (const float*)d_in[9];
    float* out = (float*)d_out;

    char* ws = (char*)d_ws;
    size_t off = 0;
    auto alloc = [&](size_t bytes) -> void* {
        void* p = ws + off;
        off = (off + bytes + 255) & ~(size_t)255;
        return p;
    };
    ushort* hb_a = (ushort*)alloc((size_t)NN * HID * 2);
    ushort* hb_b = (ushort*)alloc((size_t)NN * HID * 2);
    float*  cbuf = (float*)alloc((size_t)NN * HID * 4);
    ushort* xb   = (ushort*)alloc((size_t)NN * HID * 2);
    ushort* Wib  = (ushort*)alloc((size_t)NG * HID * 2);
    ushort* Whb  = (ushort*)alloc((size_t)NG * HID * 2);
    ushort* fcwb = (ushort*)alloc((size_t)NOUT * HID * 2);
    float*  bsum = (float*)alloc((size_t)NG * 4);
    int*    rp   = (int*)alloc((size_t)(NN + 1) * 4);
    int*    deg  = (int*)alloc((size_t)NN * 4);
    int*    cur  = (int*)alloc((size_t)NN * 4);
    int*    scol = (int*)alloc((size_t)EE * 4);
    float*  sval = (float*)alloc((size_t)EE * 4);
    float*  gx   = (float*)alloc((size_t)NN * NG * 4);
    bool use_gx = (ws_size >= off);

    // conversions to bf16
    convert_bf16_kernel<<<(NN * HID / 4 + 255) / 256, 256, 0, stream>>>(x, xb, NN * HID / 4);
    convert_bf16_kernel<<<(NG * HID / 4 + 255) / 256, 256, 0, stream>>>(Wih, Wib, NG * HID / 4);
    convert_bf16_kernel<<<(NG * HID / 4 + 255) / 256, 256, 0, stream>>>(Whh, Whb, NG * HID / 4);
    convert_bf16_kernel<<<(NOUT * HID / 4 + 255) / 256, 256, 0, stream>>>(fcw, fcwb, NOUT * HID / 4);
    bsum_kernel<<<2, 256, 0, stream>>>(bih, bhh, bsum);

    // CSR build
    hipMemsetAsync(deg, 0, (size_t)NN * 4, stream);
    hist_kernel<<<EE / 256, 256, 0, stream>>>(erow, deg);
    scan_kernel<<<1, 1024, 0, stream>>>(deg, rp, cur);
    scatter_kernel<<<EE / 256, 256, 0, stream>>>(erow, ecol, eval, cur, scol, sval);

    const int GRID64 = (NN + 63) / 64;   // 1563

    if (use_gx) {
        cell0_kernel<true><<<GRID64, 256, 0, stream>>>(xb, Wib, bsum, gx, cbuf, hb_a);
        spmm_kernel<<<(NN + 3) / 4, 256, 0, stream>>>(rp, scol, sval, hb_a, hb_b);
        for (int hop = 1; hop < HOPS; ++hop) {
            lstm_mfma_kernel<true><<<GRID64, 256, 0, stream>>>(hb_b, xb, gx, Whb, Wib, bsum, cbuf, hb_a);
            spmm_kernel<<<(NN + 3) / 4, 256, 0, stream>>>(rp, scol, sval, hb_a, hb_b);
        }
    } else {
        cell0_kernel<false><<<GRID64, 256, 0, stream>>>(xb, Wib, bsum, gx, cbuf, hb_a);
        spmm_kernel<<<(NN + 3) / 4, 256, 0, stream>>>(rp, scol, sval, hb_a, hb_b);
        for (int hop = 1; hop < HOPS; ++hop) {
            lstm_mfma_kernel<false><<<GRID64, 256, 0, stream>>>(hb_b, xb, gx, Whb, Wib, bsum, cbuf, hb_a);
            spmm_kernel<<<(NN + 3) / 4, 256, 0, stream>>>(rp, scol, sval, hb_a, hb_b);
        }
    }

    final_mfma_kernel<<<GRID64, 256, 0, stream>>>(hb_b, fcwb, fcb, out);
}

// Round 4
// 2941.422 us; speedup vs baseline: 3.6662x; 1.3531x over previous
//
#include <hip/hip_runtime.h>
#include <hip/hip_bf16.h>
#include <math.h>

constexpr int NN  = 100000;   // nodes
constexpr int EE  = 3200000;  // edges
constexpr int HID = 128;
constexpr int NG  = 512;      // 4*HID
constexpr int NOUT = 64;
constexpr int HOPS = 10;

typedef __attribute__((ext_vector_type(8))) short short8;
typedef __attribute__((ext_vector_type(4))) float f32x4;

__device__ __forceinline__ ushort f2bf(float f) {
    uint u = __builtin_bit_cast(uint, f);
    u += 0x7fff + ((u >> 16) & 1);          // RNE
    return (ushort)(u >> 16);
}
__device__ __forceinline__ float bflo(uint u) { return __builtin_bit_cast(float, u << 16); }
__device__ __forceinline__ float bfhi(uint u) { return __builtin_bit_cast(float, u & 0xffff0000u); }

__device__ __forceinline__ float sigf(float v) { return 1.0f / (1.0f + __expf(-v)); }
__device__ __forceinline__ float tanh_fast(float x) {
    float t = __expf(-2.0f * fabsf(x));
    float r = (1.0f - t) / (1.0f + t);
    return copysignf(r, x);
}

__device__ __forceinline__ short8 load_frag(const ushort* p) {
    return *reinterpret_cast<const short8*>(p);
}
__device__ __forceinline__ f32x4 mfma16(short8 a, short8 b, f32x4 c) {
    return __builtin_amdgcn_mfma_f32_16x16x32_bf16(a, b, c, 0, 0, 0);
}

// ---------------------------------------------------------------------------
// fp32 -> bf16 conversion (vectorized), n4 = n/4
// ---------------------------------------------------------------------------
__global__ __launch_bounds__(256) void convert_bf16_kernel(
    const float* __restrict__ src, ushort* __restrict__ dst, int n4)
{
    int i = blockIdx.x * 256 + threadIdx.x;
    if (i < n4) {
        float4 v = reinterpret_cast<const float4*>(src)[i];
        ushort4 o;
        o.x = f2bf(v.x); o.y = f2bf(v.y); o.z = f2bf(v.z); o.w = f2bf(v.w);
        reinterpret_cast<ushort4*>(dst)[i] = o;
    }
}

__global__ __launch_bounds__(256) void bsum_kernel(
    const float* __restrict__ bih, const float* __restrict__ bhh, float* __restrict__ bsum)
{
    int i = blockIdx.x * 256 + threadIdx.x;
    if (i < NG) bsum[i] = bih[i] + bhh[i];
}

// ---------------------------------------------------------------------------
// CSR build
// ---------------------------------------------------------------------------
__global__ __launch_bounds__(256) void hist_kernel(const int* __restrict__ erow,
                                                   int* __restrict__ deg)
{
    int e = blockIdx.x * 256 + threadIdx.x;
    atomicAdd(&deg[erow[e]], 1);
}

__global__ __launch_bounds__(1024) void scan_kernel(const int* __restrict__ deg,
                                                    int* __restrict__ rp,
                                                    int* __restrict__ cur)
{
    __shared__ int tmp[1024];
    __shared__ int carry_s;
    int t = threadIdx.x;
    if (t == 0) { carry_s = 0; rp[0] = 0; }
    __syncthreads();
    for (int base = 0; base < NN; base += 1024) {
        int i = base + t;
        int v = (i < NN) ? deg[i] : 0;
        tmp[t] = v;
        __syncthreads();
        for (int off = 1; off < 1024; off <<= 1) {
            int add = (t >= off) ? tmp[t - off] : 0;
            __syncthreads();
            tmp[t] += add;
            __syncthreads();
        }
        int incl = tmp[t] + carry_s;
        if (i < NN) { rp[i + 1] = incl; cur[i] = incl - v; }
        __syncthreads();
        if (t == 1023) carry_s = incl;
        __syncthreads();
    }
}

__global__ __launch_bounds__(256) void scatter_kernel(
    const int* __restrict__ erow, const int* __restrict__ ecol,
    const float* __restrict__ eval, int* __restrict__ cur,
    int* __restrict__ scol, float* __restrict__ sval)
{
    int e = blockIdx.x * 256 + threadIdx.x;
    int r = erow[e];
    int p = atomicAdd(&cur[r], 1);
    scol[p] = ecol[e];
    sval[p] = eval[e];
}

// ---------------------------------------------------------------------------
// Fused LSTM cell, wave-specialized gates.
// Block = 32 rows (NN = 3125*32 exactly), 4 waves.
// Wave w computes gate-row-blocks n = 4*nI + w (nI=0..7): i/f/g/o blocks for
// one hidden col are n, n+8, n+16, n+24 — all congruent mod 4 — so the LSTM
// elementwise is wave-local.
// c is stored in a per-thread permuted layout (private to this kernel).
// h is transposed via LDS to standard [row][col] bf16 for the SpMM gather.
// ---------------------------------------------------------------------------
template<bool FIRST>
__global__ __launch_bounds__(256, 2) void cell_kernel(
    const ushort* __restrict__ xb, const ushort* __restrict__ hb,
    const ushort* __restrict__ Wib, const ushort* __restrict__ Whb,
    const float* __restrict__ bsum, float* __restrict__ cperm,
    ushort* __restrict__ hout)
{
    __shared__ __align__(16) ushort lds_h[32 * 136];

    const int t  = threadIdx.x;
    const int l  = t & 63;
    const int w  = t >> 6;
    const int lr = l & 15;
    const int lk = l >> 4;
    const int row0 = blockIdx.x * 32;

    // accumulators: acc[nI][rf] -> gate-col (4*nI+w)*16+lr, rows rf*16+lk*4+jj
    f32x4 acc[8][2];
#pragma unroll
    for (int nI = 0; nI < 8; ++nI) {
        float b = bsum[(4 * nI + w) * 16 + lr];
        acc[nI][0] = f32x4{b, b, b, b};
        acc[nI][1] = f32x4{b, b, b, b};
    }

    // preload A fragments (x and h), 16B each
    short8 ax[2][4];
    short8 ah[2][4];
#pragma unroll
    for (int rf = 0; rf < 2; ++rf) {
        const size_t arow = (size_t)(row0 + rf * 16 + lr) * HID + lk * 8;
#pragma unroll
        for (int ks = 0; ks < 4; ++ks) {
            ax[rf][ks] = load_frag(xb + arow + ks * 32);
            if (!FIRST) ah[rf][ks] = load_frag(hb + arow + ks * 32);
        }
    }

#pragma unroll
    for (int nI = 0; nI < 8; ++nI) {
        const int n = 4 * nI + w;
        const ushort* wip = Wib + (size_t)(n * 16 + lr) * HID + lk * 8;
        const ushort* whp = Whb + (size_t)(n * 16 + lr) * HID + lk * 8;
        short8 bi[4], bh[4];
#pragma unroll
        for (int ks = 0; ks < 4; ++ks) {
            bi[ks] = load_frag(wip + ks * 32);
            if (!FIRST) bh[ks] = load_frag(whp + ks * 32);
        }
#pragma unroll
        for (int rf = 0; rf < 2; ++rf) {
#pragma unroll
            for (int ks = 0; ks < 4; ++ks) {
                acc[nI][rf] = mfma16(ax[rf][ks], bi[ks], acc[nI][rf]);
                if (!FIRST) acc[nI][rf] = mfma16(ah[rf][ks], bh[ks], acc[nI][rf]);
            }
        }
    }

    // epilogue: LSTM elementwise; c in permuted layout, h via LDS transpose
#pragma unroll
    for (int nj = 0; nj < 2; ++nj) {
        const int col = (w + 4 * nj) * 16 + lr;
#pragma unroll
        for (int rf = 0; rf < 2; ++rf) {
            f32x4 iv = acc[nj][rf];
            f32x4 fv = acc[nj + 2][rf];
            f32x4 gv = acc[nj + 4][rf];
            f32x4 ov = acc[nj + 6][rf];
            const size_t cidx = ((((size_t)blockIdx.x * 4 + w) * 2 + nj) * 2 + rf) * 64 + l;
            f32x4 cold;
            if (FIRST) cold = f32x4{0.f, 0.f, 0.f, 0.f};
            else       cold = reinterpret_cast<const f32x4*>(cperm)[cidx];
            f32x4 cn, hn;
#pragma unroll
            for (int jj = 0; jj < 4; ++jj) {
                float c2 = sigf(fv[jj]) * cold[jj] + sigf(iv[jj]) * tanh_fast(gv[jj]);
                cn[jj] = c2;
                hn[jj] = sigf(ov[jj]) * tanh_fast(c2);
            }
            reinterpret_cast<f32x4*>(cperm)[cidx] = cn;
            const int rbase = rf * 16 + lk * 4;
#pragma unroll
            for (int jj = 0; jj < 4; ++jj)
                lds_h[(rbase + jj) * 136 + col] = f2bf(hn[jj]);
        }
    }
    __syncthreads();
    // coalesced h store: thread t moves 16 ushorts: tile row t>>3, cols (t&7)*16..+15
    // (32 rows x 128 cols = 4096 ushorts = 256 threads x 16)
    {
        const ushort* lsrc = &lds_h[(t >> 3) * 136 + (t & 7) * 16];
        short8 v0 = *reinterpret_cast<const short8*>(lsrc);
        short8 v1 = *reinterpret_cast<const short8*>(lsrc + 8);
        ushort* gdst = hout + (size_t)row0 * HID + t * 16;
        *reinterpret_cast<short8*>(gdst) = v0;
        *reinterpret_cast<short8*>(gdst + 8) = v1;
    }
}

// ---------------------------------------------------------------------------
// SpMM: hout[r,:] = sum_e val[e] * hin[col[e],:]   (bf16 in/out, fp32 accum)
// one wave per row, lane owns 2 features (dword)
// ---------------------------------------------------------------------------
__global__ __launch_bounds__(256) void spmm_kernel(
    const int* __restrict__ rp, const int* __restrict__ scol,
    const float* __restrict__ sval, const ushort* __restrict__ hin,
    ushort* __restrict__ hout)
{
    int r = blockIdx.x * 4 + (threadIdx.x >> 6);
    if (r >= NN) return;
    int l = threadIdx.x & 63;
    int beg = rp[r], end = rp[r + 1];

    float s0a = 0.f, s1a = 0.f, s0b = 0.f, s1b = 0.f;
    float s0c = 0.f, s1c = 0.f, s0d = 0.f, s1d = 0.f;
    int e = beg;
    for (; e + 4 <= end; e += 4) {
        int c0 = scol[e], c1 = scol[e + 1], c2 = scol[e + 2], c3 = scol[e + 3];
        float v0 = sval[e], v1 = sval[e + 1], v2 = sval[e + 2], v3 = sval[e + 3];
        uint g0 = *reinterpret_cast<const uint*>(hin + (size_t)c0 * HID + l * 2);
        uint g1 = *reinterpret_cast<const uint*>(hin + (size_t)c1 * HID + l * 2);
        uint g2 = *reinterpret_cast<const uint*>(hin + (size_t)c2 * HID + l * 2);
        uint g3 = *reinterpret_cast<const uint*>(hin + (size_t)c3 * HID + l * 2);
        s0a += v0 * bflo(g0); s1a += v0 * bfhi(g0);
        s0b += v1 * bflo(g1); s1b += v1 * bfhi(g1);
        s0c += v2 * bflo(g2); s1c += v2 * bfhi(g2);
        s0d += v3 * bflo(g3); s1d += v3 * bfhi(g3);
    }
    for (; e < end; ++e) {
        int c0 = scol[e];
        float v0 = sval[e];
        uint g0 = *reinterpret_cast<const uint*>(hin + (size_t)c0 * HID + l * 2);
        s0a += v0 * bflo(g0); s1a += v0 * bfhi(g0);
    }
    float s0 = (s0a + s0b) + (s0c + s0d);
    float s1 = (s1a + s1b) + (s1c + s1d);
    uint o = ((uint)f2bf(s1) << 16) | (uint)f2bf(s0);
    *reinterpret_cast<uint*>(hout + (size_t)r * HID + l * 2) = o;
}

// ---------------------------------------------------------------------------
// final: out = relu(h) @ fc_w^T + fc_b  (MFMA)
// ---------------------------------------------------------------------------
__global__ __launch_bounds__(256) void final_mfma_kernel(
    const ushort* __restrict__ hb, const ushort* __restrict__ fcwb,
    const float* __restrict__ fcb, float* __restrict__ out)
{
    const int t = threadIdx.x;
    const int l = t & 63;
    const int w = t >> 6;
    const int lr = l & 15;
    const int lk = l >> 4;
    const int row0 = blockIdx.x * 64 + w * 16;

    f32x4 acc[4];
#pragma unroll
    for (int n = 0; n < 4; ++n) {
        float b = fcb[n * 16 + lr];
        acc[n] = f32x4{b, b, b, b};
    }

    const short8 z8 = {0, 0, 0, 0, 0, 0, 0, 0};
    const int arow = row0 + lr;
    const bool aok = arow < NN;
    short8 a[4];
#pragma unroll
    for (int ks = 0; ks < 4; ++ks) {
        short8 v = aok ? load_frag(hb + (size_t)arow * HID + ks * 32 + lk * 8) : z8;
#pragma unroll
        for (int i = 0; i < 8; ++i) {
            ushort u = (ushort)v[i];
            if (u & 0x8000) v[i] = 0;   // relu in bf16
        }
        a[ks] = v;
    }

#pragma unroll
    for (int n = 0; n < 4; ++n) {
        const ushort* wp = fcwb + (size_t)(n * 16 + lr) * HID + lk * 8;
#pragma unroll
        for (int ks = 0; ks < 4; ++ks)
            acc[n] = mfma16(a[ks], load_frag(wp + ks * 32), acc[n]);
    }

#pragma unroll
    for (int n = 0; n < 4; ++n) {
#pragma unroll
        for (int j = 0; j < 4; ++j) {
            int row = row0 + lk * 4 + j;
            if (row < NN) out[(size_t)row * NOUT + n * 16 + lr] = acc[n][j];
        }
    }
}

// ---------------------------------------------------------------------------
extern "C" void kernel_launch(void* const* d_in, const int* in_sizes, int n_in,
                              void* d_out, int out_size, void* d_ws, size_t ws_size,
                              hipStream_t stream)
{
    const float* x    = (const float*)d_in[0];
    const int*   erow = (const int*)d_in[1];
    const int*   ecol = (const int*)d_in[2];
    const float* eval = (const float*)d_in[3];
    const float* Wih  = (const float*)d_in[4];
    const float* Whh  = (const float*)d_in[5];
    const float* bih  = (const float*)d_in[6];
    const float* bhh  = (const float*)d_in[7];
    const float* fcw  = (const float*)d_in[8];
    const float* fcb  = (const float*)d_in[9];
    float* out = (float*)d_out;

    char* ws = (char*)d_ws;
    size_t off = 0;
    auto alloc = [&](size_t bytes) -> void* {
        void* p = ws + off;
        off = (off + bytes + 255) & ~(size_t)255;
        return p;
    };
    ushort* hb_a  = (ushort*)alloc((size_t)NN * HID * 2);
    ushort* hb_b  = (ushort*)alloc((size_t)NN * HID * 2);
    float*  cperm = (float*)alloc((size_t)NN * HID * 4);
    ushort* xb    = (ushort*)alloc((size_t)NN * HID * 2);
    ushort* Wib   = (ushort*)alloc((size_t)NG * HID * 2);
    ushort* Whb   = (ushort*)alloc((size_t)NG * HID * 2);
    ushort* fcwb  = (ushort*)alloc((size_t)NOUT * HID * 2);
    float*  bsum  = (float*)alloc((size_t)NG * 4);
    int*    rp    = (int*)alloc((size_t)(NN + 1) * 4);
    int*    deg   = (int*)alloc((size_t)NN * 4);
    int*    cur   = (int*)alloc((size_t)NN * 4);
    int*    scol  = (int*)alloc((size_t)EE * 4);
    float*  sval  = (float*)alloc((size_t)EE * 4);
    (void)ws_size;

    // conversions to bf16
    convert_bf16_kernel<<<(NN * HID / 4 + 255) / 256, 256, 0, stream>>>(x, xb, NN * HID / 4);
    convert_bf16_kernel<<<(NG * HID / 4 + 255) / 256, 256, 0, stream>>>(Wih, Wib, NG * HID / 4);
    convert_bf16_kernel<<<(NG * HID / 4 + 255) / 256, 256, 0, stream>>>(Whh, Whb, NG * HID / 4);
    convert_bf16_kernel<<<(NOUT * HID / 4 + 255) / 256, 256, 0, stream>>>(fcw, fcwb, NOUT * HID / 4);
    bsum_kernel<<<2, 256, 0, stream>>>(bih, bhh, bsum);

    // CSR build
    hipMemsetAsync(deg, 0, (size_t)NN * 4, stream);
    hist_kernel<<<EE / 256, 256, 0, stream>>>(erow, deg);
    scan_kernel<<<1, 1024, 0, stream>>>(deg, rp, cur);
    scatter_kernel<<<EE / 256, 256, 0, stream>>>(erow, ecol, eval, cur, scol, sval);

    const int CELL_GRID = NN / 32;   // 3125

    cell_kernel<true><<<CELL_GRID, 256, 0, stream>>>(xb, hb_b, Wib, Whb, bsum, cperm, hb_a);
    spmm_kernel<<<(NN + 3) / 4, 256, 0, stream>>>(rp, scol, sval, hb_a, hb_b);
    for (int hop = 1; hop < HOPS; ++hop) {
        cell_kernel<false><<<CELL_GRID, 256, 0, stream>>>(xb, hb_b, Wib, Whb, bsum, cperm, hb_a);
        spmm_kernel<<<(NN + 3) / 4, 256, 0, stream>>>(rp, scol, sval, hb_a, hb_b);
    }

    final_mfma_kernel<<<(NN + 63) / 64, 256, 0, stream>>>(hb_b, fcwb, fcb, out);
}

// Round 5
// 2802.789 us; speedup vs baseline: 3.8475x; 1.0495x over previous
//
#include <hip/hip_runtime.h>
#include <hip/hip_bf16.h>
#include <math.h>

constexpr int NN  = 100000;   // nodes
constexpr int EE  = 3200000;  // edges
constexpr int HID = 128;
constexpr int NG  = 512;      // 4*HID
constexpr int NOUT = 64;
constexpr int HOPS = 10;
constexpr int SCAN_BLK = 1024;
constexpr int NBLK_SCAN = (NN + SCAN_BLK - 1) / SCAN_BLK;   // 98

typedef __attribute__((ext_vector_type(8))) short short8;
typedef __attribute__((ext_vector_type(4))) float f32x4;

__device__ __forceinline__ ushort f2bf(float f) {
    uint u = __builtin_bit_cast(uint, f);
    u += 0x7fff + ((u >> 16) & 1);          // RNE
    return (ushort)(u >> 16);
}
__device__ __forceinline__ float bflo(uint u) { return __builtin_bit_cast(float, u << 16); }
__device__ __forceinline__ float bfhi(uint u) { return __builtin_bit_cast(float, u & 0xffff0000u); }

__device__ __forceinline__ float sigf(float v) { return 1.0f / (1.0f + __expf(-v)); }
__device__ __forceinline__ float tanh_fast(float x) {
    float t = __expf(-2.0f * fabsf(x));
    float r = (1.0f - t) / (1.0f + t);
    return copysignf(r, x);
}

__device__ __forceinline__ short8 load_frag(const ushort* p) {
    return *reinterpret_cast<const short8*>(p);
}
__device__ __forceinline__ f32x4 mfma16(short8 a, short8 b, f32x4 c) {
    return __builtin_amdgcn_mfma_f32_16x16x32_bf16(a, b, c, 0, 0, 0);
}

// ---------------------------------------------------------------------------
// fp32 -> bf16 conversion (vectorized), n4 = n/4
// ---------------------------------------------------------------------------
__global__ __launch_bounds__(256) void convert_bf16_kernel(
    const float* __restrict__ src, ushort* __restrict__ dst, int n4)
{
    int i = blockIdx.x * 256 + threadIdx.x;
    if (i < n4) {
        float4 v = reinterpret_cast<const float4*>(src)[i];
        ushort4 o;
        o.x = f2bf(v.x); o.y = f2bf(v.y); o.z = f2bf(v.z); o.w = f2bf(v.w);
        reinterpret_cast<ushort4*>(dst)[i] = o;
    }
}

__global__ __launch_bounds__(256) void bsum_kernel(
    const float* __restrict__ bih, const float* __restrict__ bhh, float* __restrict__ bsum)
{
    int i = blockIdx.x * 256 + threadIdx.x;
    if (i < NG) bsum[i] = bih[i] + bhh[i];
}

// ---------------------------------------------------------------------------
// CSR build: histogram -> 3-stage scan -> packed scatter
// ---------------------------------------------------------------------------
__global__ __launch_bounds__(256) void hist_kernel(const int* __restrict__ erow,
                                                   int* __restrict__ deg)
{
    int e = blockIdx.x * 256 + threadIdx.x;
    atomicAdd(&deg[erow[e]], 1);
}

// stage 1: per-block (1024 elems) sum -> bsums
__global__ __launch_bounds__(SCAN_BLK) void scan1_kernel(const int* __restrict__ deg,
                                                         int* __restrict__ bsums)
{
    __shared__ int tmp[SCAN_BLK];
    int t = threadIdx.x;
    int i = blockIdx.x * SCAN_BLK + t;
    tmp[t] = (i < NN) ? deg[i] : 0;
    __syncthreads();
    for (int off = SCAN_BLK / 2; off > 0; off >>= 1) {
        if (t < off) tmp[t] += tmp[t + off];
        __syncthreads();
    }
    if (t == 0) bsums[blockIdx.x] = tmp[0];
}

// stage 2: exclusive scan of bsums (NBLK_SCAN <= 128), single block
__global__ __launch_bounds__(128) void scan2_kernel(int* __restrict__ bsums)
{
    __shared__ int tmp[128];
    int t = threadIdx.x;
    tmp[t] = (t < NBLK_SCAN) ? bsums[t] : 0;
    __syncthreads();
    for (int off = 1; off < 128; off <<= 1) {
        int add = (t >= off) ? tmp[t - off] : 0;
        __syncthreads();
        tmp[t] += add;
        __syncthreads();
    }
    if (t < NBLK_SCAN) bsums[t] = tmp[t] - ((t < NBLK_SCAN) ? 0 : 0) - (t < NBLK_SCAN ? (t == 0 ? tmp[0] : tmp[t] - tmp[t - 1]) : 0) + ((t == 0) ? 0 : tmp[t - 1]) - ((t == 0) ? 0 : tmp[t - 1]);
    // exclusive value: t==0 -> 0, else tmp[t-1]
    if (t < NBLK_SCAN) bsums[t] = (t == 0) ? 0 : tmp[t - 1];
}

// stage 3: per-block inclusive scan + block offset -> rp, cur
__global__ __launch_bounds__(SCAN_BLK) void scan3_kernel(const int* __restrict__ deg,
                                                         const int* __restrict__ bsums,
                                                         int* __restrict__ rp,
                                                         int* __restrict__ cur)
{
    __shared__ int tmp[SCAN_BLK];
    int t = threadIdx.x;
    int i = blockIdx.x * SCAN_BLK + t;
    int v = (i < NN) ? deg[i] : 0;
    tmp[t] = v;
    __syncthreads();
    for (int off = 1; off < SCAN_BLK; off <<= 1) {
        int add = (t >= off) ? tmp[t - off] : 0;
        __syncthreads();
        tmp[t] += add;
        __syncthreads();
    }
    int incl = tmp[t] + bsums[blockIdx.x];
    if (i < NN) {
        rp[i + 1] = incl;
        cur[i] = incl - v;
    }
    if (i == 0) rp[0] = 0;
}

// packed scatter: one 8B store per edge
__global__ __launch_bounds__(256) void scatter_kernel(
    const int* __restrict__ erow, const int* __restrict__ ecol,
    const float* __restrict__ eval, int* __restrict__ cur,
    int2* __restrict__ epack)
{
    int e = blockIdx.x * 256 + threadIdx.x;
    int r = erow[e];
    int p = atomicAdd(&cur[r], 1);
    int2 pk;
    pk.x = ecol[e];
    pk.y = __builtin_bit_cast(int, eval[e]);
    epack[p] = pk;
}

// ---------------------------------------------------------------------------
// Fused LSTM cell, wave-specialized gates.
// Block = 32 rows (NN = 3125*32 exactly), 4 waves.
// Wave w computes gate-row-blocks n = 4*nI + w (nI=0..7): i/f/g/o blocks for
// one hidden col are n, n+8, n+16, n+24 — all congruent mod 4 — so the LSTM
// elementwise is wave-local.
// c is stored in a per-thread permuted layout (private to this kernel).
// h is transposed via LDS to standard [row][col] bf16 for the SpMM gather.
// ---------------------------------------------------------------------------
template<bool FIRST>
__global__ __launch_bounds__(256, 2) void cell_kernel(
    const ushort* __restrict__ xb, const ushort* __restrict__ hb,
    const ushort* __restrict__ Wib, const ushort* __restrict__ Whb,
    const float* __restrict__ bsum, float* __restrict__ cperm,
    ushort* __restrict__ hout)
{
    __shared__ __align__(16) ushort lds_h[32 * 136];

    const int t  = threadIdx.x;
    const int l  = t & 63;
    const int w  = t >> 6;
    const int lr = l & 15;
    const int lk = l >> 4;
    const int row0 = blockIdx.x * 32;

    // accumulators: acc[nI][rf] -> gate-col (4*nI+w)*16+lr, rows rf*16+lk*4+jj
    f32x4 acc[8][2];
#pragma unroll
    for (int nI = 0; nI < 8; ++nI) {
        float b = bsum[(4 * nI + w) * 16 + lr];
        acc[nI][0] = f32x4{b, b, b, b};
        acc[nI][1] = f32x4{b, b, b, b};
    }

    // preload A fragments (x and h), 16B each
    short8 ax[2][4];
    short8 ah[2][4];
#pragma unroll
    for (int rf = 0; rf < 2; ++rf) {
        const size_t arow = (size_t)(row0 + rf * 16 + lr) * HID + lk * 8;
#pragma unroll
        for (int ks = 0; ks < 4; ++ks) {
            ax[rf][ks] = load_frag(xb + arow + ks * 32);
            if (!FIRST) ah[rf][ks] = load_frag(hb + arow + ks * 32);
        }
    }

#pragma unroll
    for (int nI = 0; nI < 8; ++nI) {
        const int n = 4 * nI + w;
        const ushort* wip = Wib + (size_t)(n * 16 + lr) * HID + lk * 8;
        const ushort* whp = Whb + (size_t)(n * 16 + lr) * HID + lk * 8;
        short8 bi[4], bh[4];
#pragma unroll
        for (int ks = 0; ks < 4; ++ks) {
            bi[ks] = load_frag(wip + ks * 32);
            if (!FIRST) bh[ks] = load_frag(whp + ks * 32);
        }
#pragma unroll
        for (int rf = 0; rf < 2; ++rf) {
#pragma unroll
            for (int ks = 0; ks < 4; ++ks) {
                acc[nI][rf] = mfma16(ax[rf][ks], bi[ks], acc[nI][rf]);
                if (!FIRST) acc[nI][rf] = mfma16(ah[rf][ks], bh[ks], acc[nI][rf]);
            }
        }
    }

    // epilogue: LSTM elementwise; c in permuted layout, h via LDS transpose
#pragma unroll
    for (int nj = 0; nj < 2; ++nj) {
        const int col = (w + 4 * nj) * 16 + lr;
#pragma unroll
        for (int rf = 0; rf < 2; ++rf) {
            f32x4 iv = acc[nj][rf];
            f32x4 fv = acc[nj + 2][rf];
            f32x4 gv = acc[nj + 4][rf];
            f32x4 ov = acc[nj + 6][rf];
            const size_t cidx = ((((size_t)blockIdx.x * 4 + w) * 2 + nj) * 2 + rf) * 64 + l;
            f32x4 cold;
            if (FIRST) cold = f32x4{0.f, 0.f, 0.f, 0.f};
            else       cold = reinterpret_cast<const f32x4*>(cperm)[cidx];
            f32x4 cn, hn;
#pragma unroll
            for (int jj = 0; jj < 4; ++jj) {
                float c2 = sigf(fv[jj]) * cold[jj] + sigf(iv[jj]) * tanh_fast(gv[jj]);
                cn[jj] = c2;
                hn[jj] = sigf(ov[jj]) * tanh_fast(c2);
            }
            reinterpret_cast<f32x4*>(cperm)[cidx] = cn;
            const int rbase = rf * 16 + lk * 4;
#pragma unroll
            for (int jj = 0; jj < 4; ++jj)
                lds_h[(rbase + jj) * 136 + col] = f2bf(hn[jj]);
        }
    }
    __syncthreads();
    // coalesced h store: thread t moves 16 ushorts: tile row t>>3, cols (t&7)*16..+15
    {
        const ushort* lsrc = &lds_h[(t >> 3) * 136 + (t & 7) * 16];
        short8 v0 = *reinterpret_cast<const short8*>(lsrc);
        short8 v1 = *reinterpret_cast<const short8*>(lsrc + 8);
        ushort* gdst = hout + (size_t)row0 * HID + t * 16;
        *reinterpret_cast<short8*>(gdst) = v0;
        *reinterpret_cast<short8*>(gdst + 8) = v1;
    }
}

// ---------------------------------------------------------------------------
// SpMM: hout[r,:] = sum_e val[e] * hin[col[e],:]   (bf16 in/out, fp32 accum)
// one wave per row, lane owns 2 features (dword); packed (col,val) stream
// ---------------------------------------------------------------------------
__global__ __launch_bounds__(256) void spmm_kernel(
    const int* __restrict__ rp, const int2* __restrict__ epack,
    const ushort* __restrict__ hin, ushort* __restrict__ hout)
{
    int r = blockIdx.x * 4 + (threadIdx.x >> 6);
    if (r >= NN) return;
    int l = threadIdx.x & 63;
    int beg = rp[r], end = rp[r + 1];

    float s0a = 0.f, s1a = 0.f, s0b = 0.f, s1b = 0.f;
    float s0c = 0.f, s1c = 0.f, s0d = 0.f, s1d = 0.f;
    int e = beg;
    for (; e + 4 <= end; e += 4) {
        int2 p0 = epack[e], p1 = epack[e + 1], p2 = epack[e + 2], p3 = epack[e + 3];
        float v0 = __builtin_bit_cast(float, p0.y);
        float v1 = __builtin_bit_cast(float, p1.y);
        float v2 = __builtin_bit_cast(float, p2.y);
        float v3 = __builtin_bit_cast(float, p3.y);
        uint g0 = *reinterpret_cast<const uint*>(hin + (size_t)p0.x * HID + l * 2);
        uint g1 = *reinterpret_cast<const uint*>(hin + (size_t)p1.x * HID + l * 2);
        uint g2 = *reinterpret_cast<const uint*>(hin + (size_t)p2.x * HID + l * 2);
        uint g3 = *reinterpret_cast<const uint*>(hin + (size_t)p3.x * HID + l * 2);
        s0a += v0 * bflo(g0); s1a += v0 * bfhi(g0);
        s0b += v1 * bflo(g1); s1b += v1 * bfhi(g1);
        s0c += v2 * bflo(g2); s1c += v2 * bfhi(g2);
        s0d += v3 * bflo(g3); s1d += v3 * bfhi(g3);
    }
    for (; e < end; ++e) {
        int2 p0 = epack[e];
        float v0 = __builtin_bit_cast(float, p0.y);
        uint g0 = *reinterpret_cast<const uint*>(hin + (size_t)p0.x * HID + l * 2);
        s0a += v0 * bflo(g0); s1a += v0 * bfhi(g0);
    }
    float s0 = (s0a + s0b) + (s0c + s0d);
    float s1 = (s1a + s1b) + (s1c + s1d);
    uint o = ((uint)f2bf(s1) << 16) | (uint)f2bf(s0);
    *reinterpret_cast<uint*>(hout + (size_t)r * HID + l * 2) = o;
}

// ---------------------------------------------------------------------------
// final: out = relu(h) @ fc_w^T + fc_b  (MFMA)
// ---------------------------------------------------------------------------
__global__ __launch_bounds__(256) void final_mfma_kernel(
    const ushort* __restrict__ hb, const ushort* __restrict__ fcwb,
    const float* __restrict__ fcb, float* __restrict__ out)
{
    const int t = threadIdx.x;
    const int l = t & 63;
    const int w = t >> 6;
    const int lr = l & 15;
    const int lk = l >> 4;
    const int row0 = blockIdx.x * 64 + w * 16;

    f32x4 acc[4];
#pragma unroll
    for (int n = 0; n < 4; ++n) {
        float b = fcb[n * 16 + lr];
        acc[n] = f32x4{b, b, b, b};
    }

    const short8 z8 = {0, 0, 0, 0, 0, 0, 0, 0};
    const int arow = row0 + lr;
    const bool aok = arow < NN;
    short8 a[4];
#pragma unroll
    for (int ks = 0; ks < 4; ++ks) {
        short8 v = aok ? load_frag(hb + (size_t)arow * HID + ks * 32 + lk * 8) : z8;
#pragma unroll
        for (int i = 0; i < 8; ++i) {
            ushort u = (ushort)v[i];
            if (u & 0x8000) v[i] = 0;   // relu in bf16
        }
        a[ks] = v;
    }

#pragma unroll
    for (int n = 0; n < 4; ++n) {
        const ushort* wp = fcwb + (size_t)(n * 16 + lr) * HID + lk * 8;
#pragma unroll
        for (int ks = 0; ks < 4; ++ks)
            acc[n] = mfma16(a[ks], load_frag(wp + ks * 32), acc[n]);
    }

#pragma unroll
    for (int n = 0; n < 4; ++n) {
#pragma unroll
        for (int j = 0; j < 4; ++j) {
            int row = row0 + lk * 4 + j;
            if (row < NN) out[(size_t)row * NOUT + n * 16 + lr] = acc[n][j];
        }
    }
}

// ---------------------------------------------------------------------------
extern "C" void kernel_launch(void* const* d_in, const int* in_sizes, int n_in,
                              void* d_out, int out_size, void* d_ws, size_t ws_size,
                              hipStream_t stream)
{
    const float* x    = (const float*)d_in[0];
    const int*   erow = (const int*)d_in[1];
    const int*   ecol = (const int*)d_in[2];
    const float* eval = (const float*)d_in[3];
    const float* Wih  = (const float*)d_in[4];
    const float* Whh  = (const float*)d_in[5];
    const float* bih  = (const float*)d_in[6];
    const float* bhh  = (const float*)d_in[7];
    const float* fcw  = (const float*)d_in[8];
    const float* fcb  = (const float*)d_in[9];
    float* out = (float*)d_out;

    char* ws = (char*)d_ws;
    size_t off = 0;
    auto alloc = [&](size_t bytes) -> void* {
        void* p = ws + off;
        off = (off + bytes + 255) & ~(size_t)255;
        return p;
    };
    ushort* hb_a  = (ushort*)alloc((size_t)NN * HID * 2);
    ushort* hb_b  = (ushort*)alloc((size_t)NN * HID * 2);
    float*  cperm = (float*)alloc((size_t)NN * HID * 4);
    ushort* xb    = (ushort*)alloc((size_t)NN * HID * 2);
    ushort* Wib   = (ushort*)alloc((size_t)NG * HID * 2);
    ushort* Whb   = (ushort*)alloc((size_t)NG * HID * 2);
    ushort* fcwb  = (ushort*)alloc((size_t)NOUT * HID * 2);
    float*  bsum  = (float*)alloc((size_t)NG * 4);
    int*    rp    = (int*)alloc((size_t)(NN + 1) * 4);
    int*    deg   = (int*)alloc((size_t)NN * 4);
    int*    cur   = (int*)alloc((size_t)NN * 4);
    int*    bsums = (int*)alloc((size_t)NBLK_SCAN * 4);
    int2*   epack = (int2*)alloc((size_t)EE * 8);
    (void)ws_size;

    // conversions to bf16
    convert_bf16_kernel<<<(NN * HID / 4 + 255) / 256, 256, 0, stream>>>(x, xb, NN * HID / 4);
    convert_bf16_kernel<<<(NG * HID / 4 + 255) / 256, 256, 0, stream>>>(Wih, Wib, NG * HID / 4);
    convert_bf16_kernel<<<(NG * HID / 4 + 255) / 256, 256, 0, stream>>>(Whh, Whb, NG * HID / 4);
    convert_bf16_kernel<<<(NOUT * HID / 4 + 255) / 256, 256, 0, stream>>>(fcw, fcwb, NOUT * HID / 4);
    bsum_kernel<<<2, 256, 0, stream>>>(bih, bhh, bsum);

    // CSR build
    hipMemsetAsync(deg, 0, (size_t)NN * 4, stream);
    hist_kernel<<<EE / 256, 256, 0, stream>>>(erow, deg);
    scan1_kernel<<<NBLK_SCAN, SCAN_BLK, 0, stream>>>(deg, bsums);
    scan2_kernel<<<1, 128, 0, stream>>>(bsums);
    scan3_kernel<<<NBLK_SCAN, SCAN_BLK, 0, stream>>>(deg, bsums, rp, cur);
    scatter_kernel<<<EE / 256, 256, 0, stream>>>(erow, ecol, eval, cur, epack);

    const int CELL_GRID = NN / 32;   // 3125

    cell_kernel<true><<<CELL_GRID, 256, 0, stream>>>(xb, hb_b, Wib, Whb, bsum, cperm, hb_a);
    spmm_kernel<<<(NN + 3) / 4, 256, 0, stream>>>(rp, epack, hb_a, hb_b);
    for (int hop = 1; hop < HOPS; ++hop) {
        cell_kernel<false><<<CELL_GRID, 256, 0, stream>>>(xb, hb_b, Wib, Whb, bsum, cperm, hb_a);
        spmm_kernel<<<(NN + 3) / 4, 256, 0, stream>>>(rp, epack, hb_a, hb_b);
    }

    final_mfma_kernel<<<(NN + 63) / 64, 256, 0, stream>>>(hb_b, fcwb, fcb, out);
}